// Round 1
// 139.974 us; speedup vs baseline: 1.0091x; 1.0091x over previous
//
#include <hip/hip_runtime.h>
#include <stdint.h>

#define N 1024
#define BATCH 32
#define NFILL 4096   // zero-fill blocks in the fused kernel: 4096 * 2048 float4 = 128 MiB

// ---------------------------------------------------------------------------
// Kernel A: counting-sort positions. 16 blocks per row, 256 threads each.
//   Each block builds the row's 1024 keys in LDS (redundant, cheap), then
//   counts descending-stable sort positions for its 64 assigned elements.
//   4 threads per element, each covering a 256-key quarter-range.
//   (unchanged from the verified previous round)
// ---------------------------------------------------------------------------
__global__ __launch_bounds__(256) void count_kernel(const float* __restrict__ x,
                                                    int* __restrict__ pos_g) {
    __shared__ uint64_t keys[N];      // 8 KB
    __shared__ int      partial[256]; // 1 KB

    const int row   = blockIdx.x >> 4;
    const int chunk = blockIdx.x & 15;
    const int t     = threadIdx.x;

    // ---- build all keys for this row --------------------------------------
    const float4 xq = reinterpret_cast<const float4*>(x + row * N)[t];
    {
        const float vv[4] = {xq.x, xq.y, xq.z, xq.w};
        const int j0 = t << 2;
        #pragma unroll
        for (int e = 0; e < 4; ++e) {
            uint32_t u = __float_as_uint(vv[e]);
            u ^= (u & 0x80000000u) ? 0xFFFFFFFFu : 0x80000000u;  // monotone map
            // descending, stable: position = #{k : key_k > key_j}
            keys[j0 + e] = (((uint64_t)u) << 10) | (uint64_t)(1023 - (j0 + e));
        }
    }
    __syncthreads();

    // ---- count: element e over key quarter [q*256, q*256+256) -------------
    const int e = (chunk << 6) + (t & 63);
    const int q = t >> 6;                    // wave-uniform
    const uint64_t kk = keys[e];
    const int kbeg = q << 8;
    int c = 0;
    #pragma unroll 4
    for (int k = kbeg; k < kbeg + 256; k += 4) {
        c += (int)(keys[k    ] > kk);
        c += (int)(keys[k + 1] > kk);
        c += (int)(keys[k + 2] > kk);
        c += (int)(keys[k + 3] > kk);
    }
    partial[t] = c;
    __syncthreads();

    if (t < 64)
        pos_g[row * N + e] = partial[t] + partial[t + 64] + partial[t + 128] + partial[t + 192];
}

// ---------------------------------------------------------------------------
// Kernel FB (fused): blocks [0, BATCH) compute per-row soft-ranks (verbatim
//   rank pipeline from the verified previous round); blocks [BATCH, BATCH+NFILL)
//   zero-fill the entire output with pure streaming dwordx4 stores.
//   The zeros are rank-independent, so the mandatory 134 MB write overlaps
//   the latency-bound 32-block rank computation instead of serializing
//   behind it. Rank blocks are FIRST in the grid so they dispatch first.
// ---------------------------------------------------------------------------
__global__ __launch_bounds__(256) void fused_ranks_fill(const float* __restrict__ x,
                                                        const int* __restrict__ pos_g,
                                                        float* __restrict__ ranks,
                                                        float* __restrict__ out) {
    if (blockIdx.x >= BATCH) {
        // ---- zero-fill branch: block owns a contiguous 32 KB span ---------
        const int fid = blockIdx.x - BATCH;
        float4* o = reinterpret_cast<float4*>(out) + (size_t)fid * 2048 + threadIdx.x;
        const float4 z = make_float4(0.0f, 0.0f, 0.0f, 0.0f);
        #pragma unroll
        for (int i = 0; i < 8; ++i) o[i * 256] = z;
        return;
    }

    // ---- rank branch (one block per batch row) ----------------------------
    __shared__ float    ss[N];          // sorted values (descending)
    __shared__ float    yv[N];          // y = s + (i - 512)  (centered)
    __shared__ double   csum[N];        // inclusive prefix of yv (double)
    __shared__ int      segid[N];       // run id per sorted position
    __shared__ int      run_start[N+1]; // run boundary positions
    __shared__ float    run_mean[N];    // final (centered) mean per run
    __shared__ double   stk_sum[N];     // PAV stack: block sums
    __shared__ int      stk_cnt[N];     // PAV stack: element counts
    __shared__ int      stk_runs[N];    // PAV stack: runs per block
    __shared__ double   wsumD[4];
    __shared__ int      wsumI[4];

    const int b = blockIdx.x;
    const int t = threadIdx.x;
    const int j0 = t << 2;
    const int lane = t & 63;
    const int wid = t >> 6;

    // ---- load row + positions, scatter into sorted order ------------------
    const float4 xq = reinterpret_cast<const float4*>(x + b * N)[t];
    const int4   pq = reinterpret_cast<const int4*>(pos_g + b * N)[t];
    ss[pq.x] = xq.x; ss[pq.y] = xq.y; ss[pq.z] = xq.z; ss[pq.w] = xq.w;
    __syncthreads();

    // ---- y[i] = s[i] + (i - 512)  (centered for precision) ----------------
    float4 yq;
    {
        const float4 sq = reinterpret_cast<const float4*>(ss)[t];
        yq.x = sq.x + (float)(j0 - 512);
        yq.y = sq.y + (float)(j0 - 511);
        yq.z = sq.z + (float)(j0 - 510);
        yq.w = sq.w + (float)(j0 - 509);
        reinterpret_cast<float4*>(yv)[t] = yq;
    }
    __syncthreads();

    // ---- descent flags + thread-local inclusive scans ---------------------
    const float ye[4] = {yq.x, yq.y, yq.z, yq.w};
    int    fl[4];          // raw flags
    int    lf[4];          // local inclusive flag scan
    double lys[4];         // local inclusive y scan
    {
        float prev = (j0 == 0) ? -1.0e30f : yv[j0 - 1];
        double accy = 0.0; int accf = 0;
        #pragma unroll
        for (int e = 0; e < 4; ++e) {
            const int f = (prev > ye[e]) ? 1 : 0;   // strict descent = run start
            prev = ye[e];
            fl[e] = f;
            accf += f;             lf[e]  = accf;
            accy += (double)ye[e]; lys[e] = accy;
        }
    }
    // ---- wave-level inclusive scan of thread totals -----------------------
    double vy = lys[3]; int vf = lf[3];
    #pragma unroll
    for (int off = 1; off < 64; off <<= 1) {
        const double oy = __shfl_up(vy, off);
        const int    of = __shfl_up(vf, off);
        if (lane >= off) { vy += oy; vf += of; }
    }
    if (lane == 63) { wsumD[wid] = vy; wsumI[wid] = vf; }
    __syncthreads();
    // ---- cross-wave offsets, per-element inclusive values -----------------
    {
        double basey = vy - lys[3]; int basef = vf - lf[3];
        for (int w = 0; w < wid; ++w) { basey += wsumD[w]; basef += wsumI[w]; }
        #pragma unroll
        for (int e = 0; e < 4; ++e) {
            const int p   = j0 + e;
            const int seg = basef + lf[e];
            segid[p] = seg;
            csum[p]  = basey + lys[e];
            if (fl[e]) run_start[seg] = p;   // unique writer per seg >= 1
        }
        if (t == 0) run_start[0] = 0;
    }
    __syncthreads();

    // ---- PAV over runs (thread 0; R is tiny for near-monotone y) ----------
    if (t == 0) {
        const int R = segid[N - 1] + 1;
        run_start[R] = N;
        int sp = 0;
        for (int r = 0; r < R; ++r) {
            const int a   = run_start[r];
            const int bnd = run_start[r + 1];
            double s = csum[bnd - 1] - ((a > 0) ? csum[a - 1] : 0.0);
            int    c = bnd - a;
            int    nr = 1;
            // pool while top block's mean < new block's mean
            while (sp > 0 && s * (double)stk_cnt[sp - 1] > stk_sum[sp - 1] * (double)c) {
                s  += stk_sum[sp - 1];
                c  += stk_cnt[sp - 1];
                nr += stk_runs[sp - 1];
                --sp;
            }
            stk_sum[sp] = s; stk_cnt[sp] = c; stk_runs[sp] = nr; ++sp;
        }
        int rc = 0;
        for (int e2 = 0; e2 < sp; ++e2) {
            const float m = (float)(stk_sum[e2] / (double)stk_cnt[e2]);
            for (int q2 = 0; q2 < stk_runs[e2]; ++q2) run_mean[rc++] = m;
        }
    }
    __syncthreads();

    // ---- ranks[j] = x[j] - (sol - 512) ------------------------------------
    float4 r4;
    r4.x = xq.x - run_mean[segid[pq.x]] + 512.0f;
    r4.y = xq.y - run_mean[segid[pq.y]] + 512.0f;
    r4.z = xq.z - run_mean[segid[pq.z]] + 512.0f;
    r4.w = xq.w - run_mean[segid[pq.w]] + 512.0f;
    reinterpret_cast<float4*>(ranks + b * N)[t] = r4;
}

// ---------------------------------------------------------------------------
// Kernel S: scatter the <=2 nonzeros per output row.
//   out[b,j,i] = relu(1 - |r - (i+1)|) is a width-2 triangle: nonzero only at
//   i+1 = floor(r) (value 1-frac) and i+1 = floor(r)+1 (value frac).
//   Numerically identical to the dense per-element computation (including
//   near-integer ranks: the third candidate slot evaluates to exactly 0).
//   One thread per (b,j) row; coalesced rank load, <=2 scattered 4 B stores.
// ---------------------------------------------------------------------------
__global__ __launch_bounds__(256) void scatter_kernel(const float* __restrict__ ranks,
                                                      float* __restrict__ out) {
    const int row = blockIdx.x * 256 + threadIdx.x;   // row = b*N + j, 32768 rows
    const float r = ranks[row];
    const float f = floorf(r);
    const int   i1 = (int)f;            // nonzero at i+1 == i1 and i+1 == i1+1
    const float frac = r - f;
    float* o = out + (size_t)row * N;
    if (i1 >= 1 && i1 <= N) o[i1 - 1] = 1.0f - frac;
    if (i1 >= 0 && i1 <  N) o[i1]     = frac;
}

extern "C" void kernel_launch(void* const* d_in, const int* in_sizes, int n_in,
                              void* d_out, int out_size, void* d_ws, size_t ws_size,
                              hipStream_t stream) {
    const float* x = (const float*)d_in[0];
    float* out = (float*)d_out;
    int*   pos_g = (int*)d_ws;                        // 32K ints  = 128 KB
    float* ranks = (float*)d_ws + BATCH * N;          // 32K floats = 128 KB

    count_kernel<<<BATCH * 16, 256, 0, stream>>>(x, pos_g);
    fused_ranks_fill<<<BATCH + NFILL, 256, 0, stream>>>(x, pos_g, ranks, out);
    scatter_kernel<<<(BATCH * N) / 256, 256, 0, stream>>>(ranks, out);
}